// Round 29
// baseline (321.024 us; speedup 1.0000x reference)
//
#include <hip/hip_runtime.h>

// ---------------------------------------------------------------------------
// Pipeline (intermediates bf16, f32 accum):
//   x (N,C,T,V) f32 --transpose--> XTP (N,T+2,V,C) bf16 (boundary frames = 0)
//   LNXP = LN(XTP, ln1)                  [26000 rows; 3x dedup vs (B,L)]
//   QKVP = LNXP @ [Wq|Wk|Wv|WqWp] + b    [one MFMA dispatch, grid.y=4]
//   PK = attpool2(QP,KP rows; PQ kept in LDS)
//   k_chain (ONE dispatch, 1200 blocks of 64 rows — full middle section)
//   out = H-window-contraction @ c2w + c2b    [MFMA K=768, f32 transposed]
// r29: GEMM2-4 in k_chain stream B WEIGHTS GLOBAL->REGISTERS (2-deep named
// dbuf bA/bB, unroll 1 -> static frag indices, ~32 live VGPRs) — removes ALL
// barriers/waitcnts from 24 of 32 K-steps (r28 analysis: ~4400cy/step vs
// ~300cy issued = depth-1 LDS prefetch leaves full L2 latency exposed;
// deeper LDS dbuf forbidden by occupancy r10/m132). Weights are L2-resident
// across 1200 blocks; per-frag pattern = 16 rows x 64B. GEMM1 keeps the
// r20/r25 counted-vmcnt 2-barrier AS/BS pipeline (A produced on the fly).
// Validated: K=256 GEMM1 algebra (r28), AS/BS chunk swizzle (r22), attpool
// uint2 (r24), attpool2 fusion + A-hoist (r25). r26 spill + r27 1-barrier
// reverted.
// GEMM geometry: BM=64, BN=256, BK=32, 512 thr (8 waves 2x4).
// ---------------------------------------------------------------------------

#define DI __device__ __forceinline__

constexpr int CC   = 256;
constexpr int CL   = 75;
constexpr int CV   = 25;
constexpr int CT   = 128;
constexpr int TP   = 130;          // T+2 padded frames
constexpr int MPAD = 8 * TP * CV;  // 26000
constexpr int MBL  = 1024 * CL;    // 76800
constexpr int MOUT = 8 * CT * CV;  // 25600
constexpr float SM_SCALE = 0.17677669529663687f;  // 1/sqrt(32)

typedef __bf16 bf16x8 __attribute__((ext_vector_type(8)));
typedef float f32x4 __attribute__((ext_vector_type(4)));

DI float bf2f(unsigned short u) { return __uint_as_float(((unsigned)u) << 16); }
DI float bf2f_lo(unsigned u) { return __uint_as_float(u << 16); }
DI float bf2f_hi(unsigned u) { return __uint_as_float(u & 0xffff0000u); }
DI unsigned short f2bf(float f) {
  unsigned u = __float_as_uint(f);
  u += 0x7fffu + ((u >> 16) & 1u);
  return (unsigned short)(u >> 16);
}
DI unsigned packbf(float a, float b) {
  return (unsigned)f2bf(a) | ((unsigned)f2bf(b) << 16);
}
DI float geluf(float x) { return 0.5f * x * (1.f + erff(x * 0.70710678118654752440f)); }

// async global->LDS, 16B per lane (dest = wave-uniform base + lane*16)
DI void gll16(const unsigned short* g, unsigned short* l) {
  __builtin_amdgcn_global_load_lds(
      (const __attribute__((address_space(1))) unsigned int*)g,
      (__attribute__((address_space(3))) unsigned int*)l, 16, 0, 0);
}

// (B,L) row -> padded-frame row: r=(b,l), b=n*128+t, l=w*25+v -> (n*130+t+w)*25+v
DI int arow(int r) {
  int b = r / CL;
  int l = r - b * CL;
  int w = l / CV;
  int v = l - w * CV;
  int t = b & (CT - 1);
  int n = b >> 7;
  return (n * TP + t + w) * CV + v;
}

// ---- x (N,C,T,V) f32 -> XTP (N,T+2,V,C) bf16, interior frames ----
__global__ __launch_bounds__(256) void k_transpose(const float* __restrict__ x,
                                                   unsigned short* __restrict__ xtp) {
  __shared__ float tile[32][33];
  const int n = blockIdx.z;
  const int c0 = blockIdx.x * 32;
  const int tv0 = blockIdx.y * 32;
  const int tx = threadIdx.x & 31, ty = threadIdx.x >> 5;
#pragma unroll
  for (int j = 0; j < 32; j += 8) {
    tile[ty + j][tx] = x[((size_t)(n * CC + c0 + ty + j)) * 3200 + tv0 + tx];
  }
  __syncthreads();
#pragma unroll
  for (int j = 0; j < 32; j += 8) {
    int tv = tv0 + ty + j;
    int st = tv / CV, v = tv - st * CV;
    size_t row = ((size_t)n * TP + st + 1) * CV + v;
    xtp[row * CC + c0 + tx] = f2bf(tile[tx][ty + j]);
  }
}

// ---- zero the boundary frames (st = -1 and st = T) ----
__global__ __launch_bounds__(256) void k_zero_pad(unsigned short* __restrict__ xtp) {
  int i = blockIdx.x * 256 + threadIdx.x;  // 400*256 = 102400 exact
  int c = i & 255;
  int rid = i >> 8;
  int n = rid / 50;
  int rem = rid - n * 50;
  int side = rem / 25;
  int v = rem - side * 25;
  size_t row = ((size_t)n * TP + side * (TP - 1)) * CV + v;
  xtp[row * CC + c] = 0;
}

// ---- weight transpose+convert: dst[n*stride + off + k] = f2bf(src[k*256+n]) ----
struct TJobs {
  const float* src[9];
  unsigned short* dst[9];
  int stride[9];
  int off[9];
};
__global__ __launch_bounds__(256) void k_wtrans(TJobs J) {
  __shared__ float tile[32][33];
  const int j = blockIdx.z;
  const float* src = J.src[j];
  unsigned short* dst = J.dst[j];
  const int stride = J.stride[j], off = J.off[j];
  const int k0 = blockIdx.x * 32, n0 = blockIdx.y * 32;
  const int tx = threadIdx.x & 31, ty = threadIdx.x >> 5;
#pragma unroll
  for (int jj = 0; jj < 32; jj += 8)
    tile[ty + jj][tx] = src[(size_t)(k0 + ty + jj) * 256 + n0 + tx];
  __syncthreads();
#pragma unroll
  for (int jj = 0; jj < 32; jj += 8)
    dst[(size_t)(n0 + ty + jj) * stride + off + k0 + tx] = f2bf(tile[tx][ty + jj]);
}

// ---- fused weight products: dst[n*256+k] = bf16( (A@Wp)[k][n] ) ----
// blockIdx.y = 0: A = Wt -> fusedB;  1: A = Wq -> WqWpT (QKV slab 3)
__global__ __launch_bounds__(256) void k_wtwp(const float* __restrict__ Wt,
                                              const float* __restrict__ Wq,
                                              const float* __restrict__ Wp,
                                              unsigned short* __restrict__ fusedB,
                                              unsigned short* __restrict__ WqWpT) {
  __shared__ float wrow[256];
  const int k = blockIdx.x, n = threadIdx.x;
  const float* src = blockIdx.y ? Wq : Wt;
  unsigned short* dst = blockIdx.y ? WqWpT : fusedB;
  wrow[n] = src[(size_t)k * 256 + n];
  __syncthreads();
  float acc = 0.f;
  for (int j = 0; j < 256; ++j) acc = fmaf(wrow[j], Wp[(size_t)j * 256 + n], acc);
  dst[(size_t)n * 256 + k] = f2bf(acc);
}

// ---- bias2[n] = bp[n] + bt@Wp; bias3 = [bq | bk | bv | bq@Wp] ----
__global__ __launch_bounds__(256) void k_bias2(const float* __restrict__ bt,
                                               const float* __restrict__ Wp,
                                               const float* __restrict__ bp,
                                               const float* __restrict__ bq,
                                               const float* __restrict__ bk,
                                               const float* __restrict__ bv,
                                               float* __restrict__ bias2,
                                               float* __restrict__ bias3) {
  const int n = threadIdx.x;
  float acc = bp[n];
  float accq = 0.f;
  for (int j = 0; j < 256; ++j) {
    const float w = Wp[(size_t)j * 256 + n];
    acc = fmaf(bt[j], w, acc);
    accq = fmaf(bq[j], w, accq);
  }
  bias2[n] = acc;
  bias3[n] = bq[n];
  bias3[256 + n] = bk[n];
  bias3[512 + n] = bv[n];
  bias3[768 + n] = accq;
}

// ---- LayerNorm: one wave per row, 4 rows per block (MPAD pre-pass) ----
__global__ __launch_bounds__(256) void k_ln4(const unsigned short* __restrict__ X,
                                             const float* __restrict__ g,
                                             const float* __restrict__ b,
                                             unsigned short* __restrict__ Y) {
  const int row = blockIdx.x * 4 + (threadIdx.x >> 6);
  const int lane = threadIdx.x & 63;
  const uint2 u = *(const uint2*)(X + (size_t)row * CC + lane * 4);
  const float x0 = bf2f_lo(u.x), x1 = bf2f_hi(u.x), x2 = bf2f_lo(u.y), x3 = bf2f_hi(u.y);
  float s = x0 + x1 + x2 + x3;
  float q = x0 * x0 + x1 * x1 + x2 * x2 + x3 * x3;
#pragma unroll
  for (int o = 32; o; o >>= 1) { s += __shfl_xor(s, o); q += __shfl_xor(q, o); }
  const float mean = s * (1.f / CC);
  const float var = q * (1.f / CC) - mean * mean;
  const float rs = rsqrtf(var + 1e-5f);
  const float4 g4 = *(const float4*)(g + lane * 4);
  const float4 b4 = *(const float4*)(b + lane * 4);
  uint2 o2;
  o2.x = packbf((x0 - mean) * rs * g4.x + b4.x, (x1 - mean) * rs * g4.y + b4.y);
  o2.y = packbf((x2 - mean) * rs * g4.z + b4.z, (x3 - mean) * rs * g4.w + b4.w);
  *(uint2*)(Y + (size_t)row * CC + lane * 4) = o2;
}

// ---- pipelined MFMA bf16 GEMM (QKV + OUT), counted-vmcnt 2-barrier ----
// AMODE 0: direct (A via global_load_lds); 4: H window gather (reg-staged A)
// EPI: 0 bias (bf16 LDS-bounced coalesced store); 4 float4 transposed f32
// MULTI: blockIdx.y selects weight/bias/output slab (QKV fusion, 4 slabs)
template <int AMODE, int EPI, int KD, bool MULTI>
__global__ __launch_bounds__(512) void k_mgemm(const unsigned short* __restrict__ A,
                                               const unsigned short* __restrict__ BwT,
                                               const float* __restrict__ bias,
                                               unsigned short* __restrict__ Cout,
                                               float* __restrict__ FOut,
                                               int M) {
  if constexpr (MULTI) {
    const int z = blockIdx.y;
    BwT += (size_t)z * (256 * 256);
    bias += z * 256;
    Cout += (size_t)z * MPAD * CC;
  }
  // SH elems: As0 [0,2048) As1 [2048,4096) Bs0 [4096,12288) Bs1 [12288,20480)
  // epilogue overlays SH as 64 x 260 bf16 C tile
  __shared__ unsigned short SH[20480];
  const int tid = threadIdx.x;
  const int lane = tid & 63;
  const int wid = tid >> 6;
  const int wm = wid >> 2, wn = wid & 3;
  const int r0 = blockIdx.x * 64;
  f32x4 acc[2][4] = {};

  const bool sa = tid < 256;
  const int rA = r0 + (tid >> 2);
  const int rAc = (rA < M) ? rA : (M - 1);  // clamped: garbage rows feed masked outputs only
  const int segs = ((tid & 3) ^ ((tid >> 3) & 3)) * 8;  // swizzled source chunk
  int hrb = 0;
  if (sa && AMODE == 4 && rA < M) {
    const int nb = rA / 3200, rr = rA - nb * 3200;
    const int tq = rr / 25, vq = rr - tq * 25;
    hrb = (nb * CT + tq) * CL + vq;
  }

  auto loadA4 = [&](int k0) -> uint4 {
    uint4 u = make_uint4(0, 0, 0, 0);
    if (!(sa && rA < M)) return u;
    const int w = k0 >> 8;
    u = *(const uint4*)(A + (size_t)(hrb + w * CV) * CC + (k0 & 255) + segs);
    return u;
  };
  auto stageB = [&](int buf, int k0) {
    unsigned short* bs = SH + 4096 + buf * 8192;
#pragma unroll
    for (int pp = 0; pp < 2; ++pp) {
      const int s = tid + pp * 512;
      const int cs = ((s & 3) ^ ((s >> 3) & 3)) * 8;  // inverse-swizzled source
      gll16(BwT + (size_t)(s >> 2) * KD + k0 + cs, bs + s * 8);
    }
  };
  auto stageAg = [&](int buf, int k0) {  // unconditional per wave (waves 0-3)
    if (sa) gll16(A + (size_t)rAc * CC + k0 + segs, SH + buf * 2048 + tid * 8);
  };
  const int swl = ((lane & 15) >> 1) & 3;  // read-side chunk swizzle selector
  auto mfmaStep = [&](int cur) {
    const unsigned short* as = SH + cur * 2048;
    const unsigned short* bs = SH + 4096 + cur * 8192;
    bf16x8 af[2], bfr[4];
#pragma unroll
    for (int mi = 0; mi < 2; ++mi)
      af[mi] = *(const bf16x8*)(as + (wm * 32 + mi * 16 + (lane & 15)) * 32 +
                                (((lane >> 4) ^ swl) * 8));
#pragma unroll
    for (int ni = 0; ni < 4; ++ni)
      bfr[ni] = *(const bf16x8*)(bs + (wn * 64 + ni * 16 + (lane & 15)) * 32 +
                                 (((lane >> 4) ^ swl) * 8));
#pragma unroll
    for (int mi = 0; mi < 2; ++mi)
#pragma unroll
      for (int ni = 0; ni < 4; ++ni)
        acc[mi][ni] = __builtin_amdgcn_mfma_f32_16x16x32_bf16(af[mi], bfr[ni], acc[mi][ni], 0, 0, 0);
  };

  constexpr int NT = KD / 32;
  if constexpr (AMODE == 0) {
    // r20-validated counted pipeline (A via gll16)
    asm volatile("s_waitcnt vmcnt(0)" ::: "memory");
    stageB(0, 0);
    stageAg(0, 0);
    for (int t = 0; t < NT; ++t) {
      const int cur = t & 1;
      const bool more = (t + 1 < NT);
      if (more) { stageB(cur ^ 1, (t + 1) * 32); stageAg(cur ^ 1, (t + 1) * 32); }
      if (wid < 4) {  // stager waves: 3 gll16/step in flight
        if (more) asm volatile("s_waitcnt vmcnt(3)" ::: "memory");
        else      asm volatile("s_waitcnt vmcnt(0)" ::: "memory");
      } else {
        if (more) asm volatile("s_waitcnt vmcnt(2)" ::: "memory");
        else      asm volatile("s_waitcnt vmcnt(0)" ::: "memory");
      }
      __builtin_amdgcn_s_barrier();       // BAR_A: buf-cur fully landed
      asm volatile("" ::: "memory");
      mfmaStep(cur);
      asm volatile("s_waitcnt lgkmcnt(0)" ::: "memory");  // ds_reads retired
      __builtin_amdgcn_s_barrier();       // BAR_B: safe to overwrite buf cur
      asm volatile("" ::: "memory");
    }
    __syncthreads();  // before epilogue overlays SH
  } else {
    // counted pipeline with reg-staged A (loadA BEFORE stageB: retire order)
    {
      const uint4 a0 = loadA4(0);
      stageB(0, 0);
      if (sa) *(uint4*)(SH + tid * 8) = a0;
    }
    for (int t = 0; t < NT; ++t) {
      const int cur = t & 1;
      const bool more = (t + 1 < NT);
      if (more) {
        const uint4 an = loadA4((t + 1) * 32);
        stageB(cur ^ 1, (t + 1) * 32);
        if (sa) *(uint4*)(SH + (cur ^ 1) * 2048 + tid * 8) = an;
      }
      asm volatile("s_waitcnt lgkmcnt(0)" ::: "memory");  // AS ds_writes visible
      if (more) asm volatile("s_waitcnt vmcnt(2)" ::: "memory");
      else      asm volatile("s_waitcnt vmcnt(0)" ::: "memory");
      __builtin_amdgcn_s_barrier();       // BAR_A
      asm volatile("" ::: "memory");
      mfmaStep(cur);
      asm volatile("s_waitcnt lgkmcnt(0)" ::: "memory");
      __builtin_amdgcn_s_barrier();       // BAR_B
      asm volatile("" ::: "memory");
    }
    if constexpr (EPI == 0) __syncthreads();
  }

  const int ln15 = lane & 15, lq = lane >> 4;
  if constexpr (EPI == 4) {
#pragma unroll
    for (int mi = 0; mi < 2; ++mi) {
#pragma unroll
      for (int ni = 0; ni < 4; ++ni) {
        const int col = wn * 64 + ni * 16 + ln15;
        const float bcol = bias[col];
        const int rbase = r0 + wm * 32 + mi * 16 + lq * 4;
        const int nb = rbase / 3200, rr = rbase - nb * 3200;
        float4 v;
        v.x = acc[mi][ni][0] + bcol;
        v.y = acc[mi][ni][1] + bcol;
        v.z = acc[mi][ni][2] + bcol;
        v.w = acc[mi][ni][3] + bcol;
        *(float4*)(FOut + (size_t)nb * 819200 + (size_t)col * 3200 + rr) = v;
      }
    }
  } else {
    constexpr int LDC = 260;
#pragma unroll
    for (int mi = 0; mi < 2; ++mi) {
#pragma unroll
      for (int ni = 0; ni < 4; ++ni) {
        const int col = wn * 64 + ni * 16 + ln15;
        const float bcol = bias[col];
#pragma unroll
        for (int rg = 0; rg < 4; ++rg) {
          const int lrow = wm * 32 + mi * 16 + lq * 4 + rg;
          SH[lrow * LDC + col] = f2bf(acc[mi][ni][rg] + bcol);
        }
      }
    }
    __syncthreads();
#pragma unroll
    for (int i = 0; i < 4; ++i) {
      const int idx = tid + i * 512;
      const int row = idx >> 5, ch = idx & 31;
      const int gr = r0 + row;
      if (gr < M)
        *(uint4*)(Cout + (size_t)gr * CC + ch * 8) = *(const uint4*)&SH[row * LDC + ch * 8];
    }
  }
}

// ---- fused middle chain: ATT -> LN -> W1(gelu) -> W2(+res) -> LN -> c1w(gelu)
// One block per 64 rows of (B,L). GEMM1: counted-vmcnt 2-barrier (AS/BS).
// GEMM2-4 (r29): B weights stream global->regs, 2-deep named dbuf, ZERO
// barriers in the K-loop (ACT read-only; phase syncthreads protect rewrites).
__global__ __launch_bounds__(512, 4) void k_chain(
    const unsigned short* __restrict__ VP, const float* __restrict__ PK,
    const unsigned short* __restrict__ XTP, const unsigned short* __restrict__ QWPP,
    const unsigned short* __restrict__ fusedB, const float* __restrict__ bias2,
    const unsigned short* __restrict__ W1T, const float* __restrict__ b1,
    const unsigned short* __restrict__ W2T, const float* __restrict__ b2,
    const float* __restrict__ ffn_g, const float* __restrict__ ffn_b,
    const unsigned short* __restrict__ c1wT, const float* __restrict__ c1b,
    const float* __restrict__ tn_g, const float* __restrict__ tn_b,
    unsigned short* __restrict__ Hout) {
  constexpr int LDC = 264;  // 528B row stride: 16B-aligned b128 reads, ~2-way banks
  __shared__ unsigned short SH[16896 + 4096 + 16384];  // ACT | AS dbuf | BS dbuf
  unsigned short* ACT = SH;
  unsigned short* AS = SH + 16896;
  unsigned short* BS = SH + 16896 + 4096;
  const int tid = threadIdx.x;
  const int lane = tid & 63, wid = tid >> 6;
  const int wm = wid >> 2, wn = wid & 3;
  const int ln15 = lane & 15, lq = lane >> 4;
  const int swl = (ln15 >> 1) & 3;  // read-side chunk swizzle selector (GEMM1 LDS)
  const int r0 = blockIdx.x * 64;

  const bool sa = tid < 256;
  const int rA = r0 + (tid >> 2);
  const int segs = ((tid & 3) ^ ((tid >> 3) & 3)) * 8;  // swizzled source chunk
  int ar = 0, bb = 0;
  if (sa) { ar = arow(rA); bb = rA / CL; }
  // per-lane residual row indices (rows wm*32+mi*16+lq*4+rg), hoisted divs
  int xrow[8];
#pragma unroll
  for (int i = 0; i < 8; ++i)
    xrow[i] = arow(r0 + wm * 32 + (i >> 2) * 16 + lq * 4 + (i & 3));

  auto stageB = [&](const unsigned short* BwT, int KD, int buf, int k0) {
    unsigned short* bs = BS + buf * 8192;
#pragma unroll
    for (int pp = 0; pp < 2; ++pp) {
      const int s = tid + pp * 512;
      const int cs = ((s & 3) ^ ((s >> 3) & 3)) * 8;  // inverse-swizzled source
      gll16(BwT + (size_t)(s >> 2) * KD + k0 + cs, bs + s * 8);
    }
  };
  // A for GEMM1: VP row gathered+scaled by per-channel PK (pack to bf16)
  auto loadA5 = [&](int k0) -> uint4 {
    uint4 u = make_uint4(0, 0, 0, 0);
    if (!sa) return u;
    const int kg = k0 + segs;
    const uint4 t4 = *(const uint4*)(VP + (size_t)ar * CC + kg);
    const float* sv = PK + bb * CC + kg;
    const float4 s0 = *(const float4*)sv;
    const float4 s1 = *(const float4*)(sv + 4);
    u.x = packbf(bf2f_lo(t4.x) * s0.x, bf2f_hi(t4.x) * s0.y);
    u.y = packbf(bf2f_lo(t4.y) * s0.z, bf2f_hi(t4.y) * s0.w);
    u.z = packbf(bf2f_lo(t4.z) * s1.x, bf2f_hi(t4.z) * s1.y);
    u.w = packbf(bf2f_lo(t4.w) * s1.z, bf2f_hi(t4.w) * s1.w);
    return u;
  };
  auto ln_inplace = [&](const float* g, const float* b) {
    const float4 g4 = *(const float4*)(g + lane * 4);
    const float4 b4 = *(const float4*)(b + lane * 4);
#pragma unroll
    for (int rr = 0; rr < 8; ++rr) {
      const int row = wid * 8 + rr;
      const uint2 u = *(const uint2*)(ACT + row * LDC + lane * 4);
      const float x0 = bf2f_lo(u.x), x1 = bf2f_hi(u.x);
      const float x2 = bf2f_lo(u.y), x3 = bf2f_hi(u.y);
      float s = x0 + x1 + x2 + x3;
      float q = x0 * x0 + x1 * x1 + x2 * x2 + x3 * x3;
#pragma unroll
      for (int o = 32; o; o >>= 1) { s += __shfl_xor(s, o); q += __shfl_xor(q, o); }
      const float mean = s * (1.f / CC);
      const float var = q * (1.f / CC) - mean * mean;
      const float rs = rsqrtf(var + 1e-5f);
      uint2 o2;
      o2.x = packbf((x0 - mean) * rs * g4.x + b4.x, (x1 - mean) * rs * g4.y + b4.y);
      o2.y = packbf((x2 - mean) * rs * g4.z + b4.z, (x3 - mean) * rs * g4.w + b4.w);
      *(uint2*)(ACT + row * LDC + lane * 4) = o2;
    }
  };
  // 64x256 GEMM, A from ACT (LDS, read-only), B from GLOBAL->regs (r29).
  // 2-deep named double-buffer bA/bB; unroll 1 keeps indices static and
  // prevents full-unroll register renaming (r26 spill lesson). No barriers.
  auto gemmRB = [&](const unsigned short* BwT, f32x4 (&a)[2][4]) {
    const unsigned short* bp = BwT + (size_t)(wn * 64 + ln15) * 256 + lq * 8;
    const unsigned short* ap = ACT + (wm * 32 + ln15) * LDC + lq * 8;
    bf16x8 bA[4], bB[4];
#pragma unroll
    for (int ni = 0; ni < 4; ++ni) bA[ni] = *(const bf16x8*)(bp + ni * 16 * 256);
#pragma unroll 1
    for (int tt = 0; tt < 4; ++tt) {
      const int t0 = tt * 2, t1 = t0 + 1;
#pragma unroll
      for (int ni = 0; ni < 4; ++ni)
        bB[ni] = *(const bf16x8*)(bp + ni * 16 * 256 + t1 * 32);
      {
        bf16x8 af0[2];
#pragma unroll
        for (int mi = 0; mi < 2; ++mi)
          af0[mi] = *(const bf16x8*)(ap + mi * 16 * LDC + t0 * 32);
#pragma unroll
        for (int mi = 0; mi < 2; ++mi)
#pragma unroll
          for (int ni = 0; ni < 4; ++ni)
            a[mi][ni] = __builtin_amdgcn_mfma_f32_16x16x32_bf16(af0[mi], bA[ni], a[mi][ni], 0, 0, 0);
      }
      if (tt < 3) {
#pragma unroll
        for (int ni = 0; ni < 4; ++ni)
          bA[ni] = *(const bf16x8*)(bp + ni * 16 * 256 + (t0 + 2) * 32);
      }
      {
        bf16x8 af1[2];
#pragma unroll
        for (int mi = 0; mi < 2; ++mi)
          af1[mi] = *(const bf16x8*)(ap + mi * 16 * LDC + t1 * 32);
#pragma unroll
        for (int mi = 0; mi < 2; ++mi)
#pragma unroll
          for (int ni = 0; ni < 4; ++ni)
            a[mi][ni] = __builtin_amdgcn_mfma_f32_16x16x32_bf16(af1[mi], bB[ni], a[mi][ni], 0, 0, 0);
      }
    }
  };

  // -------- GEMM1: ATTc = (VPg*pk) @ WtWp (K=256), counted 2-barrier --------
  f32x4 acc[2][4] = {};
  {
    const uint4 a0 = loadA5(0);            // A-loads BEFORE stageB (retire order)
    stageB(fusedB, 256, 0, 0);
    if (sa) *(uint4*)(AS + tid * 8) = a0;  // pack-wait leaves B(0) in flight
  }
  for (int t = 0; t < 8; ++t) {
    const int cur = t & 1;
    const bool more = (t + 1 < 8);
    if (more) {
      const uint4 an = loadA5((t + 1) * 32);
      stageB(fusedB, 256, cur ^ 1, (t + 1) * 32);
      if (sa) *(uint4*)(AS + (cur ^ 1) * 2048 + tid * 8) = an;
    }
    asm volatile("s_waitcnt lgkmcnt(0)" ::: "memory");  // AS ds_writes visible
    if (more) asm volatile("s_waitcnt vmcnt(2)" ::: "memory");
    else      asm volatile("s_waitcnt vmcnt(0)" ::: "memory");
    __builtin_amdgcn_s_barrier();       // BAR_A
    asm volatile("" ::: "memory");
    {
      bf16x8 af[2], bfr[4];
#pragma unroll
      for (int mi = 0; mi < 2; ++mi)
        af[mi] = *(const bf16x8*)(AS + cur * 2048 + (wm * 32 + mi * 16 + ln15) * 32 +
                                  ((lq ^ swl) * 8));
#pragma unroll
      for (int ni = 0; ni < 4; ++ni)
        bfr[ni] = *(const bf16x8*)(BS + cur * 8192 + (wn * 64 + ni * 16 + ln15) * 32 +
                                   ((lq ^ swl) * 8));
#pragma unroll
      for (int mi = 0; mi < 2; ++mi)
#pragma unroll
        for (int ni = 0; ni < 4; ++ni)
          acc[mi][ni] = __builtin_amdgcn_mfma_f32_16x16x32_bf16(af[mi], bfr[ni], acc[mi][ni], 0, 0, 0);
    }
    asm volatile("s_waitcnt lgkmcnt(0)" ::: "memory");
    __builtin_amdgcn_s_barrier();       // BAR_B
    asm volatile("" ::: "memory");
  }
  // epilogue: attres = acc + bias2 + QWPP gather (q@Wp) + XTP gather (residual)
  f32x4 attres[2][4];
#pragma unroll
  for (int mi = 0; mi < 2; ++mi) {
#pragma unroll
    for (int ni = 0; ni < 4; ++ni) {
      const int col = wn * 64 + ni * 16 + ln15;
      const float bcol = bias2[col];
#pragma unroll
      for (int rg = 0; rg < 4; ++rg) {
        const size_t ro = (size_t)xrow[mi * 4 + rg] * CC + col;
        attres[mi][ni][rg] = acc[mi][ni][rg] + bcol + bf2f(QWPP[ro]) + bf2f(XTP[ro]);
        ACT[(wm * 32 + mi * 16 + lq * 4 + rg) * LDC + col] = f2bf(attres[mi][ni][rg]);
      }
    }
  }
  __syncthreads();           // ACT visible
  ln_inplace(ffn_g, ffn_b);  // F = LN(ATT)
  __syncthreads();

  // -------- GEMM2: G = gelu(F @ W1 + b1) --------
  f32x4 acc2[2][4] = {};
  gemmRB(W1T, acc2);
  __syncthreads();  // all ACT (F) reads done
#pragma unroll
  for (int mi = 0; mi < 2; ++mi)
#pragma unroll
    for (int ni = 0; ni < 4; ++ni) {
      const int col = wn * 64 + ni * 16 + ln15;
      const float bcol = b1[col];
#pragma unroll
      for (int rg = 0; rg < 4; ++rg)
        ACT[(wm * 32 + mi * 16 + lq * 4 + rg) * LDC + col] = f2bf(geluf(acc2[mi][ni][rg] + bcol));
    }
  __syncthreads();

  // -------- GEMM3: Y = G @ W2 + b2 + attres --------
  f32x4 acc3[2][4] = {};
  gemmRB(W2T, acc3);
  __syncthreads();  // all ACT (G) reads done
#pragma unroll
  for (int mi = 0; mi < 2; ++mi)
#pragma unroll
    for (int ni = 0; ni < 4; ++ni) {
      const int col = wn * 64 + ni * 16 + ln15;
      const float bcol = b2[col];
#pragma unroll
      for (int rg = 0; rg < 4; ++rg)
        ACT[(wm * 32 + mi * 16 + lq * 4 + rg) * LDC + col] =
            f2bf(acc3[mi][ni][rg] + bcol + attres[mi][ni][rg]);
    }
  __syncthreads();
  ln_inplace(tn_g, tn_b);  // TN = LN(Y)
  __syncthreads();

  // -------- GEMM4: H = gelu(TN @ c1w + c1b) --------
  f32x4 acc4[2][4] = {};
  gemmRB(c1wT, acc4);
  __syncthreads();  // all ACT (TN) reads done
#pragma unroll
  for (int mi = 0; mi < 2; ++mi)
#pragma unroll
    for (int ni = 0; ni < 4; ++ni) {
      const int col = wn * 64 + ni * 16 + ln15;
      const float bcol = c1b[col];
#pragma unroll
      for (int rg = 0; rg < 4; ++rg)
        ACT[(wm * 32 + mi * 16 + lq * 4 + rg) * LDC + col] = f2bf(geluf(acc4[mi][ni][rg] + bcol));
    }
  __syncthreads();
#pragma unroll
  for (int i = 0; i < 4; ++i) {
    const int idx = tid + i * 512;  // 2048 chunks = 64 rows x 32
    const int row = idx >> 5, ch = idx & 31;
    *(uint4*)(Hout + (size_t)(r0 + row) * CC + ch * 8) = *(const uint4*)&ACT[row * LDC + ch * 8];
  }
}

// ---- fused attention pools: one block per b; PQ lives in LDS (r25) ----
// Phase Q: stage QP rows -> logits rows@Wqa+bqa -> softmax -> PQ (LDS).
// Phase K: restage KP rows -> logits (rows.*pq)@Wka+bka -> softmax -> PK.
__global__ __launch_bounds__(256) void k_attpool2(
    const unsigned short* __restrict__ QPr, const unsigned short* __restrict__ KPr,
    const float* __restrict__ Wqa, const float* __restrict__ bqa,
    const float* __restrict__ Wka, const float* __restrict__ bka,
    float* __restrict__ PK) {
  __shared__ unsigned short rows[CL * CC];  // 38400 B (reused Q then K)
  __shared__ float uu[8 * 258];             // [h][c] strided 258
  __shared__ float lg[8 * 76];              // logits per (h,l)
  __shared__ float inv8[8];
  __shared__ float pq[256];
  __shared__ int arl[CL];
  const int b = blockIdx.x;
  const int t = threadIdx.x;

  if (t < CL) arl[t] = arow(b * CL + t);
  __syncthreads();

  auto dot_phase = [&](const float* b8) {
    const int c0 = (t & 63) * 4;
    for (int i = t; i < CL * 8; i += 256) {
      const int h = i / CL, l = i - h * CL;
      float acc = b8[h];
#pragma unroll 4
      for (int jj = 0; jj < CC; jj += 4) {
        const int c = (c0 + jj) & 255;
        const uint2 pr = *(const uint2*)&rows[l * CC + c];
        acc = fmaf(bf2f_lo(pr.x), uu[h * 258 + c], acc);
        acc = fmaf(bf2f_hi(pr.x), uu[h * 258 + c + 1], acc);
        acc = fmaf(bf2f_lo(pr.y), uu[h * 258 + c + 2], acc);
        acc = fmaf(bf2f_hi(pr.y), uu[h * 258 + c + 3], acc);
      }
      lg[h * 76 + l] = acc * SM_SCALE;
    }
  };
  auto softmax8 = [&]() {
    if (t < 8) {
      float m = -1e30f;
      for (int l = 0; l < CL; ++l) m = fmaxf(m, lg[t * 76 + l]);
      float s = 0.f;
      for (int l = 0; l < CL; ++l) {
        const float e = __expf(lg[t * 76 + l] - m);
        lg[t * 76 + l] = e;
        s += e;
      }
      inv8[t] = 1.f / s;
    }
  };

  // -------- phase Q --------
  for (int i = t; i < CL * 32; i += 256) {
    const int r = i >> 5, seg = i & 31;
    gll16(QPr + (size_t)arl[r] * CC + seg * 8, &rows[i * 8]);
  }
  for (int i = t; i < CC * 8; i += 256) {
    const int c = i >> 3, h = i & 7;
    uu[h * 258 + c] = Wqa[c * 8 + h];
  }
  __syncthreads();  // rows(Q) + uu ready (implicit vmcnt drain)
  dot_phase(bqa);
  __syncthreads();
  softmax8();
  __syncthreads();
  {
    const int h = t >> 5;
    float acc = 0.f;
    for (int l = 0; l < CL; ++l) acc = fmaf(lg[h * 76 + l], bf2f(rows[l * CC + t]), acc);
    pq[t] = acc * inv8[h];
  }
  __syncthreads();  // pq ready; all rows(Q) reads done

  // -------- phase K --------
  for (int i = t; i < CL * 32; i += 256) {
    const int r = i >> 5, seg = i & 31;
    gll16(KPr + (size_t)arl[r] * CC + seg * 8, &rows[i * 8]);
  }
  for (int i = t; i < CC * 8; i += 256) {
    const int c = i >> 3, h = i & 7;
    uu[h * 258 + c] = pq[c] * Wka[c * 8 + h];
  }
  __syncthreads();  // rows(K) + uu ready
  dot_phase(bka);
  __syncthreads();
  softmax8();
  __syncthreads();
  {
    const int h = t >> 5;
    float acc = 0.f;
    for (int l = 0; l < CL; ++l) acc = fmaf(lg[h * 76 + l], bf2f(rows[l * CC + t]), acc);
    PK[(size_t)b * CC + t] = acc * inv8[h];
  }
}

extern "C" void kernel_launch(void* const* d_in, const int* in_sizes, int n_in,
                              void* d_out, int out_size, void* d_ws, size_t ws_size,
                              hipStream_t stream) {
  const float* x = (const float*)d_in[0];
  const float* ln1_g = (const float*)d_in[1];
  const float* ln1_b = (const float*)d_in[2];
  const float* Wq = (const float*)d_in[3];
  const float* bq = (const float*)d_in[4];
  const float* Wqa = (const float*)d_in[5];
  const float* bqa = (const float*)d_in[6];
  const float* Wk = (const float*)d_in[7];
  const float* bk = (const float*)d_in[8];
  const float* Wka = (const float*)d_in[9];
  const float* bka = (const float*)d_in[10];
  const float* Wv = (const float*)d_in[11];
  const float* bv = (const float*)d_in[12];
  const float* Wt = (const float*)d_in[13];
  const float* bt = (const float*)d_in[14];
  const float* Wp = (const float*)d_in[15];
  const float* bp = (const float*)d_in[16];
  const float* ffn_g = (const float*)d_in[17];
  const float* ffn_b = (const float*)d_in[18];
  const float* W1 = (const float*)d_in[19];
  const float* b1 = (const float*)d_in[20];
  const float* W2 = (const float*)d_in[21];
  const float* b2 = (const float*)d_in[22];
  const float* tn_g = (const float*)d_in[23];
  const float* tn_b = (const float*)d_in[24];
  const float* c1w = (const float*)d_in[25];
  const float* c1b = (const float*)d_in[26];
  const float* c2w = (const float*)d_in[27];
  const float* c2b = (const float*)d_in[28];
  float* out = (float*)d_out;

  char* wp = (char*)d_ws;
  auto alloc = [&](size_t bytes) -> char* {
    char* p = wp;
    wp += (bytes + 255) & ~(size_t)255;
    return p;
  };
  unsigned short* XTP = (unsigned short*)alloc((size_t)MPAD * CC * 2);
  unsigned short* LNXP = (unsigned short*)alloc((size_t)MPAD * CC * 2);
  unsigned short* QKVP = (unsigned short*)alloc((size_t)4 * MPAD * CC * 2);
  unsigned short* QP = QKVP;
  unsigned short* KP = QKVP + (size_t)MPAD * CC;
  unsigned short* VP = QKVP + (size_t)2 * MPAD * CC;
  unsigned short* QWPP = QKVP + (size_t)3 * MPAD * CC;
  unsigned short* Hb = (unsigned short*)alloc((size_t)MBL * CC * 2);
  float* PK = (float*)alloc((size_t)1024 * CC * 4);
  unsigned short* WqkvT = (unsigned short*)alloc((size_t)4 * 256 * 256 * 2);
  unsigned short* W1T = (unsigned short*)alloc(256 * 256 * 2);
  unsigned short* W2T = (unsigned short*)alloc(256 * 256 * 2);
  unsigned short* c1wT = (unsigned short*)alloc(256 * 256 * 2);
  unsigned short* c2wT = (unsigned short*)alloc(256 * 768 * 2);
  unsigned short* fusedB = (unsigned short*)alloc(256 * 256 * 2);  // (WtWp)^T
  float* bias2 = (float*)alloc(256 * 4);
  float* bias3 = (float*)alloc(1024 * 4);

  // weight prep: dst[n*stride+off+k] = bf16(src[k][n]); WqWp/WtWp via k_wtwp
  TJobs J;
  const float* srcs[9] = {Wq, Wk, Wv, W1, W2, c1w, c2w, c2w + 65536, c2w + 131072};
  unsigned short* dsts[9] = {WqkvT, WqkvT + 65536, WqkvT + 131072, W1T, W2T, c1wT,
                             c2wT, c2wT, c2wT};
  const int strides[9] = {256, 256, 256, 256, 256, 256, 768, 768, 768};
  const int offs[9] = {0, 0, 0, 0, 0, 0, 0, 256, 512};
  for (int i = 0; i < 9; ++i) {
    J.src[i] = srcs[i]; J.dst[i] = dsts[i]; J.stride[i] = strides[i]; J.off[i] = offs[i];
  }
  k_wtrans<<<dim3(8, 8, 9), 256, 0, stream>>>(J);
  k_wtwp<<<dim3(256, 2), 256, 0, stream>>>(Wt, Wq, Wp, fusedB, WqkvT + 3 * 65536);
  k_bias2<<<1, 256, 0, stream>>>(bt, Wp, bp, bq, bk, bv, bias2, bias3);

  k_transpose<<<dim3(8, 100, 8), 256, 0, stream>>>(x, XTP);
  k_zero_pad<<<400, 256, 0, stream>>>(XTP);
  k_ln4<<<MPAD / 4, 256, 0, stream>>>(XTP, ln1_g, ln1_b, LNXP);

  const int gP = (MPAD + 63) / 64;  // 407
  const int gO = MOUT / 64;         // 400
  // fused QKV+QWP: grid.y = 4 slabs (Q, K, V, Q@Wp)
  k_mgemm<0, 0, 256, true><<<dim3(gP, 4), 512, 0, stream>>>(
      LNXP, WqkvT, bias3, QKVP, nullptr, MPAD);

  // fused attention pools (PQ stays in LDS)
  k_attpool2<<<1024, 256, 0, stream>>>(QP, KP, Wqa, bqa, Wka, bka, PK);

  // fused middle chain: ATT -> LN -> FFN -> LN -> c1w -> H
  k_chain<<<MBL / 64, 512, 0, stream>>>(VP, PK, XTP, QWPP, fusedB, bias2,
                                        W1T, b1, W2T, b2, ffn_g, ffn_b,
                                        c1wT, c1b, tn_g, tn_b, Hb);

  k_mgemm<4, 4, 768, false><<<gO, 512, 0, stream>>>(Hb, c2wT, c2b, nullptr, out, MOUT);
}

// Round 30
// 257.434 us; speedup vs baseline: 1.2470x; 1.2470x over previous
//
#include <hip/hip_runtime.h>

// ---------------------------------------------------------------------------
// Pipeline (intermediates bf16, f32 accum):
//   x (N,C,T,V) f32 --transpose--> XTP (N,T+2,V,C) bf16 (boundary frames = 0)
//   LNXP = LN(XTP, ln1)                  [26000 rows; 3x dedup vs (B,L)]
//   QKVP = LNXP @ [Wq|Wk|Wv|WqWp] + b    [one MFMA dispatch, grid.y=4]
//   PK = attpool2(QP,KP rows; PQ kept in LDS)
//   k_chain (ONE dispatch, 1200 blocks of 64 rows — full middle section)
//   out = H-window-contraction @ c2w + c2b    [MFMA K=768, f32 transposed]
// r30: r29 POST-MORTEM — reg-B failed via L2 REQUEST RATE (16x 64B scattered
// transactions per fragment load; VGPR 64, FETCH flat -> not a spill). Fix:
// FRAGMENT-MAJOR weight layout WF[k>>3][n][k&7] for W1/W2/c1w (k_wtrans
// stride==0 mode) -> each B-fragment load = 4x 256B coalesced segments.
// gemmRB keeps r29's 2-deep named dbuf + unroll 1 + zero barriers for
// GEMM2-4. GEMM1 keeps the r20/r25 counted-vmcnt 2-barrier AS/BS pipeline.
// Validated: K=256 GEMM1 algebra (r28), AS/BS chunk swizzle (r22), attpool
// uint2 (r24), attpool2 fusion + A-hoist (r25).
// GEMM geometry: BM=64, BN=256, BK=32, 512 thr (8 waves 2x4).
// ---------------------------------------------------------------------------

#define DI __device__ __forceinline__

constexpr int CC   = 256;
constexpr int CL   = 75;
constexpr int CV   = 25;
constexpr int CT   = 128;
constexpr int TP   = 130;          // T+2 padded frames
constexpr int MPAD = 8 * TP * CV;  // 26000
constexpr int MBL  = 1024 * CL;    // 76800
constexpr int MOUT = 8 * CT * CV;  // 25600
constexpr float SM_SCALE = 0.17677669529663687f;  // 1/sqrt(32)

typedef __bf16 bf16x8 __attribute__((ext_vector_type(8)));
typedef float f32x4 __attribute__((ext_vector_type(4)));

DI float bf2f(unsigned short u) { return __uint_as_float(((unsigned)u) << 16); }
DI float bf2f_lo(unsigned u) { return __uint_as_float(u << 16); }
DI float bf2f_hi(unsigned u) { return __uint_as_float(u & 0xffff0000u); }
DI unsigned short f2bf(float f) {
  unsigned u = __float_as_uint(f);
  u += 0x7fffu + ((u >> 16) & 1u);
  return (unsigned short)(u >> 16);
}
DI unsigned packbf(float a, float b) {
  return (unsigned)f2bf(a) | ((unsigned)f2bf(b) << 16);
}
DI float geluf(float x) { return 0.5f * x * (1.f + erff(x * 0.70710678118654752440f)); }

// async global->LDS, 16B per lane (dest = wave-uniform base + lane*16)
DI void gll16(const unsigned short* g, unsigned short* l) {
  __builtin_amdgcn_global_load_lds(
      (const __attribute__((address_space(1))) unsigned int*)g,
      (__attribute__((address_space(3))) unsigned int*)l, 16, 0, 0);
}

// (B,L) row -> padded-frame row: r=(b,l), b=n*128+t, l=w*25+v -> (n*130+t+w)*25+v
DI int arow(int r) {
  int b = r / CL;
  int l = r - b * CL;
  int w = l / CV;
  int v = l - w * CV;
  int t = b & (CT - 1);
  int n = b >> 7;
  return (n * TP + t + w) * CV + v;
}

// ---- x (N,C,T,V) f32 -> XTP (N,T+2,V,C) bf16, interior frames ----
__global__ __launch_bounds__(256) void k_transpose(const float* __restrict__ x,
                                                   unsigned short* __restrict__ xtp) {
  __shared__ float tile[32][33];
  const int n = blockIdx.z;
  const int c0 = blockIdx.x * 32;
  const int tv0 = blockIdx.y * 32;
  const int tx = threadIdx.x & 31, ty = threadIdx.x >> 5;
#pragma unroll
  for (int j = 0; j < 32; j += 8) {
    tile[ty + j][tx] = x[((size_t)(n * CC + c0 + ty + j)) * 3200 + tv0 + tx];
  }
  __syncthreads();
#pragma unroll
  for (int j = 0; j < 32; j += 8) {
    int tv = tv0 + ty + j;
    int st = tv / CV, v = tv - st * CV;
    size_t row = ((size_t)n * TP + st + 1) * CV + v;
    xtp[row * CC + c0 + tx] = f2bf(tile[tx][ty + j]);
  }
}

// ---- zero the boundary frames (st = -1 and st = T) ----
__global__ __launch_bounds__(256) void k_zero_pad(unsigned short* __restrict__ xtp) {
  int i = blockIdx.x * 256 + threadIdx.x;  // 400*256 = 102400 exact
  int c = i & 255;
  int rid = i >> 8;
  int n = rid / 50;
  int rem = rid - n * 50;
  int side = rem / 25;
  int v = rem - side * 25;
  size_t row = ((size_t)n * TP + side * (TP - 1)) * CV + v;
  xtp[row * CC + c] = 0;
}

// ---- weight transpose+convert ----
// stride>0: dst[n*stride + off + k] = bf16(src[k*256+n])
// stride==0: FRAGMENT-MAJOR (r30): dst[(k>>3)*2048 + n*8 + (k&7)]
struct TJobs {
  const float* src[9];
  unsigned short* dst[9];
  int stride[9];
  int off[9];
};
__global__ __launch_bounds__(256) void k_wtrans(TJobs J) {
  __shared__ float tile[32][33];
  const int j = blockIdx.z;
  const float* src = J.src[j];
  unsigned short* dst = J.dst[j];
  const int stride = J.stride[j], off = J.off[j];
  const int k0 = blockIdx.x * 32, n0 = blockIdx.y * 32;
  const int tx = threadIdx.x & 31, ty = threadIdx.x >> 5;
#pragma unroll
  for (int jj = 0; jj < 32; jj += 8)
    tile[ty + jj][tx] = src[(size_t)(k0 + ty + jj) * 256 + n0 + tx];
  __syncthreads();
  if (stride > 0) {
#pragma unroll
    for (int jj = 0; jj < 32; jj += 8)
      dst[(size_t)(n0 + ty + jj) * stride + off + k0 + tx] = f2bf(tile[tx][ty + jj]);
  } else {
    const int k = k0 + tx;
#pragma unroll
    for (int jj = 0; jj < 32; jj += 8)
      dst[(size_t)(k >> 3) * 2048 + (size_t)(n0 + ty + jj) * 8 + (k & 7)] =
          f2bf(tile[tx][ty + jj]);
  }
}

// ---- fused weight products: dst[n*256+k] = bf16( (A@Wp)[k][n] ) ----
// blockIdx.y = 0: A = Wt -> fusedB;  1: A = Wq -> WqWpT (QKV slab 3)
__global__ __launch_bounds__(256) void k_wtwp(const float* __restrict__ Wt,
                                              const float* __restrict__ Wq,
                                              const float* __restrict__ Wp,
                                              unsigned short* __restrict__ fusedB,
                                              unsigned short* __restrict__ WqWpT) {
  __shared__ float wrow[256];
  const int k = blockIdx.x, n = threadIdx.x;
  const float* src = blockIdx.y ? Wq : Wt;
  unsigned short* dst = blockIdx.y ? WqWpT : fusedB;
  wrow[n] = src[(size_t)k * 256 + n];
  __syncthreads();
  float acc = 0.f;
  for (int j = 0; j < 256; ++j) acc = fmaf(wrow[j], Wp[(size_t)j * 256 + n], acc);
  dst[(size_t)n * 256 + k] = f2bf(acc);
}

// ---- bias2[n] = bp[n] + bt@Wp; bias3 = [bq | bk | bv | bq@Wp] ----
__global__ __launch_bounds__(256) void k_bias2(const float* __restrict__ bt,
                                               const float* __restrict__ Wp,
                                               const float* __restrict__ bp,
                                               const float* __restrict__ bq,
                                               const float* __restrict__ bk,
                                               const float* __restrict__ bv,
                                               float* __restrict__ bias2,
                                               float* __restrict__ bias3) {
  const int n = threadIdx.x;
  float acc = bp[n];
  float accq = 0.f;
  for (int j = 0; j < 256; ++j) {
    const float w = Wp[(size_t)j * 256 + n];
    acc = fmaf(bt[j], w, acc);
    accq = fmaf(bq[j], w, accq);
  }
  bias2[n] = acc;
  bias3[n] = bq[n];
  bias3[256 + n] = bk[n];
  bias3[512 + n] = bv[n];
  bias3[768 + n] = accq;
}

// ---- LayerNorm: one wave per row, 4 rows per block (MPAD pre-pass) ----
__global__ __launch_bounds__(256) void k_ln4(const unsigned short* __restrict__ X,
                                             const float* __restrict__ g,
                                             const float* __restrict__ b,
                                             unsigned short* __restrict__ Y) {
  const int row = blockIdx.x * 4 + (threadIdx.x >> 6);
  const int lane = threadIdx.x & 63;
  const uint2 u = *(const uint2*)(X + (size_t)row * CC + lane * 4);
  const float x0 = bf2f_lo(u.x), x1 = bf2f_hi(u.x), x2 = bf2f_lo(u.y), x3 = bf2f_hi(u.y);
  float s = x0 + x1 + x2 + x3;
  float q = x0 * x0 + x1 * x1 + x2 * x2 + x3 * x3;
#pragma unroll
  for (int o = 32; o; o >>= 1) { s += __shfl_xor(s, o); q += __shfl_xor(q, o); }
  const float mean = s * (1.f / CC);
  const float var = q * (1.f / CC) - mean * mean;
  const float rs = rsqrtf(var + 1e-5f);
  const float4 g4 = *(const float4*)(g + lane * 4);
  const float4 b4 = *(const float4*)(b + lane * 4);
  uint2 o2;
  o2.x = packbf((x0 - mean) * rs * g4.x + b4.x, (x1 - mean) * rs * g4.y + b4.y);
  o2.y = packbf((x2 - mean) * rs * g4.z + b4.z, (x3 - mean) * rs * g4.w + b4.w);
  *(uint2*)(Y + (size_t)row * CC + lane * 4) = o2;
}

// ---- pipelined MFMA bf16 GEMM (QKV + OUT), counted-vmcnt 2-barrier ----
// AMODE 0: direct (A via global_load_lds); 4: H window gather (reg-staged A)
// EPI: 0 bias (bf16 LDS-bounced coalesced store); 4 float4 transposed f32
// MULTI: blockIdx.y selects weight/bias/output slab (QKV fusion, 4 slabs)
template <int AMODE, int EPI, int KD, bool MULTI>
__global__ __launch_bounds__(512) void k_mgemm(const unsigned short* __restrict__ A,
                                               const unsigned short* __restrict__ BwT,
                                               const float* __restrict__ bias,
                                               unsigned short* __restrict__ Cout,
                                               float* __restrict__ FOut,
                                               int M) {
  if constexpr (MULTI) {
    const int z = blockIdx.y;
    BwT += (size_t)z * (256 * 256);
    bias += z * 256;
    Cout += (size_t)z * MPAD * CC;
  }
  // SH elems: As0 [0,2048) As1 [2048,4096) Bs0 [4096,12288) Bs1 [12288,20480)
  // epilogue overlays SH as 64 x 260 bf16 C tile
  __shared__ unsigned short SH[20480];
  const int tid = threadIdx.x;
  const int lane = tid & 63;
  const int wid = tid >> 6;
  const int wm = wid >> 2, wn = wid & 3;
  const int r0 = blockIdx.x * 64;
  f32x4 acc[2][4] = {};

  const bool sa = tid < 256;
  const int rA = r0 + (tid >> 2);
  const int rAc = (rA < M) ? rA : (M - 1);  // clamped: garbage rows feed masked outputs only
  const int segs = ((tid & 3) ^ ((tid >> 3) & 3)) * 8;  // swizzled source chunk
  int hrb = 0;
  if (sa && AMODE == 4 && rA < M) {
    const int nb = rA / 3200, rr = rA - nb * 3200;
    const int tq = rr / 25, vq = rr - tq * 25;
    hrb = (nb * CT + tq) * CL + vq;
  }

  auto loadA4 = [&](int k0) -> uint4 {
    uint4 u = make_uint4(0, 0, 0, 0);
    if (!(sa && rA < M)) return u;
    const int w = k0 >> 8;
    u = *(const uint4*)(A + (size_t)(hrb + w * CV) * CC + (k0 & 255) + segs);
    return u;
  };
  auto stageB = [&](int buf, int k0) {
    unsigned short* bs = SH + 4096 + buf * 8192;
#pragma unroll
    for (int pp = 0; pp < 2; ++pp) {
      const int s = tid + pp * 512;
      const int cs = ((s & 3) ^ ((s >> 3) & 3)) * 8;  // inverse-swizzled source
      gll16(BwT + (size_t)(s >> 2) * KD + k0 + cs, bs + s * 8);
    }
  };
  auto stageAg = [&](int buf, int k0) {  // unconditional per wave (waves 0-3)
    if (sa) gll16(A + (size_t)rAc * CC + k0 + segs, SH + buf * 2048 + tid * 8);
  };
  const int swl = ((lane & 15) >> 1) & 3;  // read-side chunk swizzle selector
  auto mfmaStep = [&](int cur) {
    const unsigned short* as = SH + cur * 2048;
    const unsigned short* bs = SH + 4096 + cur * 8192;
    bf16x8 af[2], bfr[4];
#pragma unroll
    for (int mi = 0; mi < 2; ++mi)
      af[mi] = *(const bf16x8*)(as + (wm * 32 + mi * 16 + (lane & 15)) * 32 +
                                (((lane >> 4) ^ swl) * 8));
#pragma unroll
    for (int ni = 0; ni < 4; ++ni)
      bfr[ni] = *(const bf16x8*)(bs + (wn * 64 + ni * 16 + (lane & 15)) * 32 +
                                 (((lane >> 4) ^ swl) * 8));
#pragma unroll
    for (int mi = 0; mi < 2; ++mi)
#pragma unroll
      for (int ni = 0; ni < 4; ++ni)
        acc[mi][ni] = __builtin_amdgcn_mfma_f32_16x16x32_bf16(af[mi], bfr[ni], acc[mi][ni], 0, 0, 0);
  };

  constexpr int NT = KD / 32;
  if constexpr (AMODE == 0) {
    // r20-validated counted pipeline (A via gll16)
    asm volatile("s_waitcnt vmcnt(0)" ::: "memory");
    stageB(0, 0);
    stageAg(0, 0);
    for (int t = 0; t < NT; ++t) {
      const int cur = t & 1;
      const bool more = (t + 1 < NT);
      if (more) { stageB(cur ^ 1, (t + 1) * 32); stageAg(cur ^ 1, (t + 1) * 32); }
      if (wid < 4) {  // stager waves: 3 gll16/step in flight
        if (more) asm volatile("s_waitcnt vmcnt(3)" ::: "memory");
        else      asm volatile("s_waitcnt vmcnt(0)" ::: "memory");
      } else {
        if (more) asm volatile("s_waitcnt vmcnt(2)" ::: "memory");
        else      asm volatile("s_waitcnt vmcnt(0)" ::: "memory");
      }
      __builtin_amdgcn_s_barrier();       // BAR_A: buf-cur fully landed
      asm volatile("" ::: "memory");
      mfmaStep(cur);
      asm volatile("s_waitcnt lgkmcnt(0)" ::: "memory");  // ds_reads retired
      __builtin_amdgcn_s_barrier();       // BAR_B: safe to overwrite buf cur
      asm volatile("" ::: "memory");
    }
    __syncthreads();  // before epilogue overlays SH
  } else {
    // counted pipeline with reg-staged A (loadA BEFORE stageB: retire order)
    {
      const uint4 a0 = loadA4(0);
      stageB(0, 0);
      if (sa) *(uint4*)(SH + tid * 8) = a0;
    }
    for (int t = 0; t < NT; ++t) {
      const int cur = t & 1;
      const bool more = (t + 1 < NT);
      if (more) {
        const uint4 an = loadA4((t + 1) * 32);
        stageB(cur ^ 1, (t + 1) * 32);
        if (sa) *(uint4*)(SH + (cur ^ 1) * 2048 + tid * 8) = an;
      }
      asm volatile("s_waitcnt lgkmcnt(0)" ::: "memory");  // AS ds_writes visible
      if (more) asm volatile("s_waitcnt vmcnt(2)" ::: "memory");
      else      asm volatile("s_waitcnt vmcnt(0)" ::: "memory");
      __builtin_amdgcn_s_barrier();       // BAR_A
      asm volatile("" ::: "memory");
      mfmaStep(cur);
      asm volatile("s_waitcnt lgkmcnt(0)" ::: "memory");
      __builtin_amdgcn_s_barrier();       // BAR_B
      asm volatile("" ::: "memory");
    }
    if constexpr (EPI == 0) __syncthreads();
  }

  const int ln15 = lane & 15, lq = lane >> 4;
  if constexpr (EPI == 4) {
#pragma unroll
    for (int mi = 0; mi < 2; ++mi) {
#pragma unroll
      for (int ni = 0; ni < 4; ++ni) {
        const int col = wn * 64 + ni * 16 + ln15;
        const float bcol = bias[col];
        const int rbase = r0 + wm * 32 + mi * 16 + lq * 4;
        const int nb = rbase / 3200, rr = rbase - nb * 3200;
        float4 v;
        v.x = acc[mi][ni][0] + bcol;
        v.y = acc[mi][ni][1] + bcol;
        v.z = acc[mi][ni][2] + bcol;
        v.w = acc[mi][ni][3] + bcol;
        *(float4*)(FOut + (size_t)nb * 819200 + (size_t)col * 3200 + rr) = v;
      }
    }
  } else {
    constexpr int LDC = 260;
#pragma unroll
    for (int mi = 0; mi < 2; ++mi) {
#pragma unroll
      for (int ni = 0; ni < 4; ++ni) {
        const int col = wn * 64 + ni * 16 + ln15;
        const float bcol = bias[col];
#pragma unroll
        for (int rg = 0; rg < 4; ++rg) {
          const int lrow = wm * 32 + mi * 16 + lq * 4 + rg;
          SH[lrow * LDC + col] = f2bf(acc[mi][ni][rg] + bcol);
        }
      }
    }
    __syncthreads();
#pragma unroll
    for (int i = 0; i < 4; ++i) {
      const int idx = tid + i * 512;
      const int row = idx >> 5, ch = idx & 31;
      const int gr = r0 + row;
      if (gr < M)
        *(uint4*)(Cout + (size_t)gr * CC + ch * 8) = *(const uint4*)&SH[row * LDC + ch * 8];
    }
  }
}

// ---- fused middle chain: ATT -> LN -> W1(gelu) -> W2(+res) -> LN -> c1w(gelu)
// One block per 64 rows of (B,L). GEMM1: counted-vmcnt 2-barrier (AS/BS).
// GEMM2-4 (r30): B from FRAGMENT-MAJOR global weights -> regs (256B coalesced
// segments), 2-deep named dbuf, zero barriers in the K-loop.
__global__ __launch_bounds__(512, 4) void k_chain(
    const unsigned short* __restrict__ VP, const float* __restrict__ PK,
    const unsigned short* __restrict__ XTP, const unsigned short* __restrict__ QWPP,
    const unsigned short* __restrict__ fusedB, const float* __restrict__ bias2,
    const unsigned short* __restrict__ W1F, const float* __restrict__ b1,
    const unsigned short* __restrict__ W2F, const float* __restrict__ b2,
    const float* __restrict__ ffn_g, const float* __restrict__ ffn_b,
    const unsigned short* __restrict__ c1wF, const float* __restrict__ c1b,
    const float* __restrict__ tn_g, const float* __restrict__ tn_b,
    unsigned short* __restrict__ Hout) {
  constexpr int LDC = 264;  // 528B row stride: 16B-aligned b128 reads, ~2-way banks
  __shared__ unsigned short SH[16896 + 4096 + 16384];  // ACT | AS dbuf | BS dbuf
  unsigned short* ACT = SH;
  unsigned short* AS = SH + 16896;
  unsigned short* BS = SH + 16896 + 4096;
  const int tid = threadIdx.x;
  const int lane = tid & 63, wid = tid >> 6;
  const int wm = wid >> 2, wn = wid & 3;
  const int ln15 = lane & 15, lq = lane >> 4;
  const int swl = (ln15 >> 1) & 3;  // read-side chunk swizzle selector (GEMM1 LDS)
  const int r0 = blockIdx.x * 64;

  const bool sa = tid < 256;
  const int rA = r0 + (tid >> 2);
  const int segs = ((tid & 3) ^ ((tid >> 3) & 3)) * 8;  // swizzled source chunk
  int ar = 0, bb = 0;
  if (sa) { ar = arow(rA); bb = rA / CL; }
  // per-lane residual row indices (rows wm*32+mi*16+lq*4+rg), hoisted divs
  int xrow[8];
#pragma unroll
  for (int i = 0; i < 8; ++i)
    xrow[i] = arow(r0 + wm * 32 + (i >> 2) * 16 + lq * 4 + (i & 3));

  auto stageB = [&](const unsigned short* BwT, int KD, int buf, int k0) {
    unsigned short* bs = BS + buf * 8192;
#pragma unroll
    for (int pp = 0; pp < 2; ++pp) {
      const int s = tid + pp * 512;
      const int cs = ((s & 3) ^ ((s >> 3) & 3)) * 8;  // inverse-swizzled source
      gll16(BwT + (size_t)(s >> 2) * KD + k0 + cs, bs + s * 8);
    }
  };
  // A for GEMM1: VP row gathered+scaled by per-channel PK (pack to bf16)
  auto loadA5 = [&](int k0) -> uint4 {
    uint4 u = make_uint4(0, 0, 0, 0);
    if (!sa) return u;
    const int kg = k0 + segs;
    const uint4 t4 = *(const uint4*)(VP + (size_t)ar * CC + kg);
    const float* sv = PK + bb * CC + kg;
    const float4 s0 = *(const float4*)sv;
    const float4 s1 = *(const float4*)(sv + 4);
    u.x = packbf(bf2f_lo(t4.x) * s0.x, bf2f_hi(t4.x) * s0.y);
    u.y = packbf(bf2f_lo(t4.y) * s0.z, bf2f_hi(t4.y) * s0.w);
    u.z = packbf(bf2f_lo(t4.z) * s1.x, bf2f_hi(t4.z) * s1.y);
    u.w = packbf(bf2f_lo(t4.w) * s1.z, bf2f_hi(t4.w) * s1.w);
    return u;
  };
  auto ln_inplace = [&](const float* g, const float* b) {
    const float4 g4 = *(const float4*)(g + lane * 4);
    const float4 b4 = *(const float4*)(b + lane * 4);
#pragma unroll
    for (int rr = 0; rr < 8; ++rr) {
      const int row = wid * 8 + rr;
      const uint2 u = *(const uint2*)(ACT + row * LDC + lane * 4);
      const float x0 = bf2f_lo(u.x), x1 = bf2f_hi(u.x);
      const float x2 = bf2f_lo(u.y), x3 = bf2f_hi(u.y);
      float s = x0 + x1 + x2 + x3;
      float q = x0 * x0 + x1 * x1 + x2 * x2 + x3 * x3;
#pragma unroll
      for (int o = 32; o; o >>= 1) { s += __shfl_xor(s, o); q += __shfl_xor(q, o); }
      const float mean = s * (1.f / CC);
      const float var = q * (1.f / CC) - mean * mean;
      const float rs = rsqrtf(var + 1e-5f);
      uint2 o2;
      o2.x = packbf((x0 - mean) * rs * g4.x + b4.x, (x1 - mean) * rs * g4.y + b4.y);
      o2.y = packbf((x2 - mean) * rs * g4.z + b4.z, (x3 - mean) * rs * g4.w + b4.w);
      *(uint2*)(ACT + row * LDC + lane * 4) = o2;
    }
  };
  // 64x256 GEMM, A from ACT (LDS, read-only), B from FRAGMENT-MAJOR global
  // weights (r30): WF[(k>>3)*2048 + n*8 + (k&7)] -> per-load 4x256B coalesced
  // segments. 2-deep named dbuf bA/bB; unroll 1 keeps indices static (r26
  // spill lesson). No barriers in the loop.
  auto gemmRB = [&](const unsigned short* WF, f32x4 (&a)[2][4]) {
    const unsigned short* bp = WF + (size_t)(wn * 64 + ln15) * 8 + lq * 2048;
    const unsigned short* ap = ACT + (wm * 32 + ln15) * LDC + lq * 8;
    bf16x8 bA[4], bB[4];
#pragma unroll
    for (int ni = 0; ni < 4; ++ni) bA[ni] = *(const bf16x8*)(bp + ni * 128);
#pragma unroll 1
    for (int tt = 0; tt < 4; ++tt) {
      const int t0 = tt * 2, t1 = t0 + 1;
#pragma unroll
      for (int ni = 0; ni < 4; ++ni)
        bB[ni] = *(const bf16x8*)(bp + ni * 128 + t1 * 8192);
      {
        bf16x8 af0[2];
#pragma unroll
        for (int mi = 0; mi < 2; ++mi)
          af0[mi] = *(const bf16x8*)(ap + mi * 16 * LDC + t0 * 32);
#pragma unroll
        for (int mi = 0; mi < 2; ++mi)
#pragma unroll
          for (int ni = 0; ni < 4; ++ni)
            a[mi][ni] = __builtin_amdgcn_mfma_f32_16x16x32_bf16(af0[mi], bA[ni], a[mi][ni], 0, 0, 0);
      }
      if (tt < 3) {
#pragma unroll
        for (int ni = 0; ni < 4; ++ni)
          bA[ni] = *(const bf16x8*)(bp + ni * 128 + (t0 + 2) * 8192);
      }
      {
        bf16x8 af1[2];
#pragma unroll
        for (int mi = 0; mi < 2; ++mi)
          af1[mi] = *(const bf16x8*)(ap + mi * 16 * LDC + t1 * 32);
#pragma unroll
        for (int mi = 0; mi < 2; ++mi)
#pragma unroll
          for (int ni = 0; ni < 4; ++ni)
            a[mi][ni] = __builtin_amdgcn_mfma_f32_16x16x32_bf16(af1[mi], bB[ni], a[mi][ni], 0, 0, 0);
      }
    }
  };

  // -------- GEMM1: ATTc = (VPg*pk) @ WtWp (K=256), counted 2-barrier --------
  f32x4 acc[2][4] = {};
  {
    const uint4 a0 = loadA5(0);            // A-loads BEFORE stageB (retire order)
    stageB(fusedB, 256, 0, 0);
    if (sa) *(uint4*)(AS + tid * 8) = a0;  // pack-wait leaves B(0) in flight
  }
  for (int t = 0; t < 8; ++t) {
    const int cur = t & 1;
    const bool more = (t + 1 < 8);
    if (more) {
      const uint4 an = loadA5((t + 1) * 32);
      stageB(fusedB, 256, cur ^ 1, (t + 1) * 32);
      if (sa) *(uint4*)(AS + (cur ^ 1) * 2048 + tid * 8) = an;
    }
    asm volatile("s_waitcnt lgkmcnt(0)" ::: "memory");  // AS ds_writes visible
    if (more) asm volatile("s_waitcnt vmcnt(2)" ::: "memory");
    else      asm volatile("s_waitcnt vmcnt(0)" ::: "memory");
    __builtin_amdgcn_s_barrier();       // BAR_A
    asm volatile("" ::: "memory");
    {
      bf16x8 af[2], bfr[4];
#pragma unroll
      for (int mi = 0; mi < 2; ++mi)
        af[mi] = *(const bf16x8*)(AS + cur * 2048 + (wm * 32 + mi * 16 + ln15) * 32 +
                                  ((lq ^ swl) * 8));
#pragma unroll
      for (int ni = 0; ni < 4; ++ni)
        bfr[ni] = *(const bf16x8*)(BS + cur * 8192 + (wn * 64 + ni * 16 + ln15) * 32 +
                                   ((lq ^ swl) * 8));
#pragma unroll
      for (int mi = 0; mi < 2; ++mi)
#pragma unroll
        for (int ni = 0; ni < 4; ++ni)
          acc[mi][ni] = __builtin_amdgcn_mfma_f32_16x16x32_bf16(af[mi], bfr[ni], acc[mi][ni], 0, 0, 0);
    }
    asm volatile("s_waitcnt lgkmcnt(0)" ::: "memory");
    __builtin_amdgcn_s_barrier();       // BAR_B
    asm volatile("" ::: "memory");
  }
  // epilogue: attres = acc + bias2 + QWPP gather (q@Wp) + XTP gather (residual)
  f32x4 attres[2][4];
#pragma unroll
  for (int mi = 0; mi < 2; ++mi) {
#pragma unroll
    for (int ni = 0; ni < 4; ++ni) {
      const int col = wn * 64 + ni * 16 + ln15;
      const float bcol = bias2[col];
#pragma unroll
      for (int rg = 0; rg < 4; ++rg) {
        const size_t ro = (size_t)xrow[mi * 4 + rg] * CC + col;
        attres[mi][ni][rg] = acc[mi][ni][rg] + bcol + bf2f(QWPP[ro]) + bf2f(XTP[ro]);
        ACT[(wm * 32 + mi * 16 + lq * 4 + rg) * LDC + col] = f2bf(attres[mi][ni][rg]);
      }
    }
  }
  __syncthreads();           // ACT visible
  ln_inplace(ffn_g, ffn_b);  // F = LN(ATT)
  __syncthreads();

  // -------- GEMM2: G = gelu(F @ W1 + b1) --------
  f32x4 acc2[2][4] = {};
  gemmRB(W1F, acc2);
  __syncthreads();  // all ACT (F) reads done
#pragma unroll
  for (int mi = 0; mi < 2; ++mi)
#pragma unroll
    for (int ni = 0; ni < 4; ++ni) {
      const int col = wn * 64 + ni * 16 + ln15;
      const float bcol = b1[col];
#pragma unroll
      for (int rg = 0; rg < 4; ++rg)
        ACT[(wm * 32 + mi * 16 + lq * 4 + rg) * LDC + col] = f2bf(geluf(acc2[mi][ni][rg] + bcol));
    }
  __syncthreads();

  // -------- GEMM3: Y = G @ W2 + b2 + attres --------
  f32x4 acc3[2][4] = {};
  gemmRB(W2F, acc3);
  __syncthreads();  // all ACT (G) reads done
#pragma unroll
  for (int mi = 0; mi < 2; ++mi)
#pragma unroll
    for (int ni = 0; ni < 4; ++ni) {
      const int col = wn * 64 + ni * 16 + ln15;
      const float bcol = b2[col];
#pragma unroll
      for (int rg = 0; rg < 4; ++rg)
        ACT[(wm * 32 + mi * 16 + lq * 4 + rg) * LDC + col] =
            f2bf(acc3[mi][ni][rg] + bcol + attres[mi][ni][rg]);
    }
  __syncthreads();
  ln_inplace(tn_g, tn_b);  // TN = LN(Y)
  __syncthreads();

  // -------- GEMM4: H = gelu(TN @ c1w + c1b) --------
  f32x4 acc4[2][4] = {};
  gemmRB(c1wF, acc4);
  __syncthreads();  // all ACT (TN) reads done
#pragma unroll
  for (int mi = 0; mi < 2; ++mi)
#pragma unroll
    for (int ni = 0; ni < 4; ++ni) {
      const int col = wn * 64 + ni * 16 + ln15;
      const float bcol = c1b[col];
#pragma unroll
      for (int rg = 0; rg < 4; ++rg)
        ACT[(wm * 32 + mi * 16 + lq * 4 + rg) * LDC + col] = f2bf(geluf(acc4[mi][ni][rg] + bcol));
    }
  __syncthreads();
#pragma unroll
  for (int i = 0; i < 4; ++i) {
    const int idx = tid + i * 512;  // 2048 chunks = 64 rows x 32
    const int row = idx >> 5, ch = idx & 31;
    *(uint4*)(Hout + (size_t)(r0 + row) * CC + ch * 8) = *(const uint4*)&ACT[row * LDC + ch * 8];
  }
}

// ---- fused attention pools: one block per b; PQ lives in LDS (r25) ----
// Phase Q: stage QP rows -> logits rows@Wqa+bqa -> softmax -> PQ (LDS).
// Phase K: restage KP rows -> logits (rows.*pq)@Wka+bka -> softmax -> PK.
__global__ __launch_bounds__(256) void k_attpool2(
    const unsigned short* __restrict__ QPr, const unsigned short* __restrict__ KPr,
    const float* __restrict__ Wqa, const float* __restrict__ bqa,
    const float* __restrict__ Wka, const float* __restrict__ bka,
    float* __restrict__ PK) {
  __shared__ unsigned short rows[CL * CC];  // 38400 B (reused Q then K)
  __shared__ float uu[8 * 258];             // [h][c] strided 258
  __shared__ float lg[8 * 76];              // logits per (h,l)
  __shared__ float inv8[8];
  __shared__ float pq[256];
  __shared__ int arl[CL];
  const int b = blockIdx.x;
  const int t = threadIdx.x;

  if (t < CL) arl[t] = arow(b * CL + t);
  __syncthreads();

  auto dot_phase = [&](const float* b8) {
    const int c0 = (t & 63) * 4;
    for (int i = t; i < CL * 8; i += 256) {
      const int h = i / CL, l = i - h * CL;
      float acc = b8[h];
#pragma unroll 4
      for (int jj = 0; jj < CC; jj += 4) {
        const int c = (c0 + jj) & 255;
        const uint2 pr = *(const uint2*)&rows[l * CC + c];
        acc = fmaf(bf2f_lo(pr.x), uu[h * 258 + c], acc);
        acc = fmaf(bf2f_hi(pr.x), uu[h * 258 + c + 1], acc);
        acc = fmaf(bf2f_lo(pr.y), uu[h * 258 + c + 2], acc);
        acc = fmaf(bf2f_hi(pr.y), uu[h * 258 + c + 3], acc);
      }
      lg[h * 76 + l] = acc * SM_SCALE;
    }
  };
  auto softmax8 = [&]() {
    if (t < 8) {
      float m = -1e30f;
      for (int l = 0; l < CL; ++l) m = fmaxf(m, lg[t * 76 + l]);
      float s = 0.f;
      for (int l = 0; l < CL; ++l) {
        const float e = __expf(lg[t * 76 + l] - m);
        lg[t * 76 + l] = e;
        s += e;
      }
      inv8[t] = 1.f / s;
    }
  };

  // -------- phase Q --------
  for (int i = t; i < CL * 32; i += 256) {
    const int r = i >> 5, seg = i & 31;
    gll16(QPr + (size_t)arl[r] * CC + seg * 8, &rows[i * 8]);
  }
  for (int i = t; i < CC * 8; i += 256) {
    const int c = i >> 3, h = i & 7;
    uu[h * 258 + c] = Wqa[c * 8 + h];
  }
  __syncthreads();  // rows(Q) + uu ready (implicit vmcnt drain)
  dot_phase(bqa);
  __syncthreads();
  softmax8();
  __syncthreads();
  {
    const int h = t >> 5;
    float acc = 0.f;
    for (int l = 0; l < CL; ++l) acc = fmaf(lg[h * 76 + l], bf2f(rows[l * CC + t]), acc);
    pq[t] = acc * inv8[h];
  }
  __syncthreads();  // pq ready; all rows(Q) reads done

  // -------- phase K --------
  for (int i = t; i < CL * 32; i += 256) {
    const int r = i >> 5, seg = i & 31;
    gll16(KPr + (size_t)arl[r] * CC + seg * 8, &rows[i * 8]);
  }
  for (int i = t; i < CC * 8; i += 256) {
    const int c = i >> 3, h = i & 7;
    uu[h * 258 + c] = pq[c] * Wka[c * 8 + h];
  }
  __syncthreads();  // rows(K) + uu ready
  dot_phase(bka);
  __syncthreads();
  softmax8();
  __syncthreads();
  {
    const int h = t >> 5;
    float acc = 0.f;
    for (int l = 0; l < CL; ++l) acc = fmaf(lg[h * 76 + l], bf2f(rows[l * CC + t]), acc);
    PK[(size_t)b * CC + t] = acc * inv8[h];
  }
}

extern "C" void kernel_launch(void* const* d_in, const int* in_sizes, int n_in,
                              void* d_out, int out_size, void* d_ws, size_t ws_size,
                              hipStream_t stream) {
  const float* x = (const float*)d_in[0];
  const float* ln1_g = (const float*)d_in[1];
  const float* ln1_b = (const float*)d_in[2];
  const float* Wq = (const float*)d_in[3];
  const float* bq = (const float*)d_in[4];
  const float* Wqa = (const float*)d_in[5];
  const float* bqa = (const float*)d_in[6];
  const float* Wk = (const float*)d_in[7];
  const float* bk = (const float*)d_in[8];
  const float* Wka = (const float*)d_in[9];
  const float* bka = (const float*)d_in[10];
  const float* Wv = (const float*)d_in[11];
  const float* bv = (const float*)d_in[12];
  const float* Wt = (const float*)d_in[13];
  const float* bt = (const float*)d_in[14];
  const float* Wp = (const float*)d_in[15];
  const float* bp = (const float*)d_in[16];
  const float* ffn_g = (const float*)d_in[17];
  const float* ffn_b = (const float*)d_in[18];
  const float* W1 = (const float*)d_in[19];
  const float* b1 = (const float*)d_in[20];
  const float* W2 = (const float*)d_in[21];
  const float* b2 = (const float*)d_in[22];
  const float* tn_g = (const float*)d_in[23];
  const float* tn_b = (const float*)d_in[24];
  const float* c1w = (const float*)d_in[25];
  const float* c1b = (const float*)d_in[26];
  const float* c2w = (const float*)d_in[27];
  const float* c2b = (const float*)d_in[28];
  float* out = (float*)d_out;

  char* wp = (char*)d_ws;
  auto alloc = [&](size_t bytes) -> char* {
    char* p = wp;
    wp += (bytes + 255) & ~(size_t)255;
    return p;
  };
  unsigned short* XTP = (unsigned short*)alloc((size_t)MPAD * CC * 2);
  unsigned short* LNXP = (unsigned short*)alloc((size_t)MPAD * CC * 2);
  unsigned short* QKVP = (unsigned short*)alloc((size_t)4 * MPAD * CC * 2);
  unsigned short* QP = QKVP;
  unsigned short* KP = QKVP + (size_t)MPAD * CC;
  unsigned short* VP = QKVP + (size_t)2 * MPAD * CC;
  unsigned short* QWPP = QKVP + (size_t)3 * MPAD * CC;
  unsigned short* Hb = (unsigned short*)alloc((size_t)MBL * CC * 2);
  float* PK = (float*)alloc((size_t)1024 * CC * 4);
  unsigned short* WqkvT = (unsigned short*)alloc((size_t)4 * 256 * 256 * 2);
  unsigned short* W1F = (unsigned short*)alloc(256 * 256 * 2);
  unsigned short* W2F = (unsigned short*)alloc(256 * 256 * 2);
  unsigned short* c1wF = (unsigned short*)alloc(256 * 256 * 2);
  unsigned short* c2wT = (unsigned short*)alloc(256 * 768 * 2);
  unsigned short* fusedB = (unsigned short*)alloc(256 * 256 * 2);  // (WtWp)^T
  float* bias2 = (float*)alloc(256 * 4);
  float* bias3 = (float*)alloc(1024 * 4);

  // weight prep: [n][k] for QKV/OUT; FRAGMENT-MAJOR (stride==0) for W1/W2/c1w
  TJobs J;
  const float* srcs[9] = {Wq, Wk, Wv, W1, W2, c1w, c2w, c2w + 65536, c2w + 131072};
  unsigned short* dsts[9] = {WqkvT, WqkvT + 65536, WqkvT + 131072, W1F, W2F, c1wF,
                             c2wT, c2wT, c2wT};
  const int strides[9] = {256, 256, 256, 0, 0, 0, 768, 768, 768};
  const int offs[9] = {0, 0, 0, 0, 0, 0, 0, 256, 512};
  for (int i = 0; i < 9; ++i) {
    J.src[i] = srcs[i]; J.dst[i] = dsts[i]; J.stride[i] = strides[i]; J.off[i] = offs[i];
  }
  k_wtrans<<<dim3(8, 8, 9), 256, 0, stream>>>(J);
  k_wtwp<<<dim3(256, 2), 256, 0, stream>>>(Wt, Wq, Wp, fusedB, WqkvT + 3 * 65536);
  k_bias2<<<1, 256, 0, stream>>>(bt, Wp, bp, bq, bk, bv, bias2, bias3);

  k_transpose<<<dim3(8, 100, 8), 256, 0, stream>>>(x, XTP);
  k_zero_pad<<<400, 256, 0, stream>>>(XTP);
  k_ln4<<<MPAD / 4, 256, 0, stream>>>(XTP, ln1_g, ln1_b, LNXP);

  const int gP = (MPAD + 63) / 64;  // 407
  const int gO = MOUT / 64;         // 400
  // fused QKV+QWP: grid.y = 4 slabs (Q, K, V, Q@Wp)
  k_mgemm<0, 0, 256, true><<<dim3(gP, 4), 512, 0, stream>>>(
      LNXP, WqkvT, bias3, QKVP, nullptr, MPAD);

  // fused attention pools (PQ stays in LDS)
  k_attpool2<<<1024, 256, 0, stream>>>(QP, KP, Wqa, bqa, Wka, bka, PK);

  // fused middle chain: ATT -> LN -> FFN -> LN -> c1w -> H
  k_chain<<<MBL / 64, 512, 0, stream>>>(VP, PK, XTP, QWPP, fusedB, bias2,
                                        W1F, b1, W2F, b2, ffn_g, ffn_b,
                                        c1wF, c1b, tn_g, tn_b, Hb);

  k_mgemm<4, 4, 768, false><<<gO, 512, 0, stream>>>(Hb, c2wT, c2b, nullptr, out, MOUT);
}